// Round 1
// baseline (725.870 us; speedup 1.0000x reference)
//
#include <hip/hip_runtime.h>

// GPConv3D as implicit GEMM on bf16 MFMA.
// out[(o,k)][(b,d,h,w)] = sum_{m,l,v,c,i} ga_sign(i,i^k) W[m,l,v,c,o,i^k] * x[b,c,i,d+m,h+l,w+v] + bias
// M=64 (o*8+k), K=1728 = 27 taps x 64 (c*8+i), N=8*46^3.
// This version: cvt_x pre-transposes x to [(b,z,y)][cb][x48][k32] bf16 so the main kernel
// stages via global_load_lds (16B, linear dest, zero VALU transpose, zero ds_writes).
// Both cb halves staged per z-plane -> 3 barrier phases per block (was 6).
// LDS pitch 32 (no pad): B-frag ds_read_b128 reads 1024 consecutive bytes -> conflict-free.

namespace {

constexpr int DIN = 48, DOUT = 46;
constexpr size_t X_ELEMS = 8ull * 8 * 8 * DIN * DIN * DIN;   // 56,623,104
constexpr size_t XBF_BYTES = X_ELEMS * 2;                    // 113,246,208
constexpr int APK_ELEMS = 54 * 4 * 64 * 8;                   // 110,592 bf16
constexpr int ROW_BYTES = 2 * 48 * 32 * 2;                   // 6144 B per (b,z,y) row

__host__ __device__ constexpr int popc_(int v) { int c = 0; while (v) { c += v & 1; v >>= 1; } return c; }
__host__ __device__ inline float ga_sign(int a, int b) {
  int s = 0;
  for (int t = a >> 1; t; t >>= 1) s += popc_(t & b);
  return (s & 1) ? -1.0f : 1.0f;
}

__device__ inline unsigned short f2bf(float f) {  // round-to-nearest-even
  unsigned u = __builtin_bit_cast(unsigned, f);
  u += 0x7fffu + ((u >> 16) & 1u);
  return (unsigned short)(u >> 16);
}

__device__ inline void gload_lds16(const void* g, void* l) {
  __builtin_amdgcn_global_load_lds(
      (const __attribute__((address_space(1))) unsigned int*)g,
      (__attribute__((address_space(3))) unsigned int*)l, 16, 0, 0);
}

using frag  = __attribute__((ext_vector_type(8))) short;  // 8 bf16 (4 VGPRs)
using f32x4 = __attribute__((ext_vector_type(4))) float;

// ---- prep 1: x fp32 -> bf16, transposed to [(b*48+z)*48+y][cb][x48][k32] ----
// One block per (b,z,y): reads 64 k-rows x 48 x fp32, LDS-transposes, writes 6144 B contiguous.
__global__ __launch_bounds__(256) void cvt_x(const float* __restrict__ x,
                                             unsigned short* __restrict__ xt) {
  const int row = blockIdx.x;                 // (b*48+z)*48+y
  const int t = threadIdx.x;
  const int k = t >> 2, c4 = t & 3;           // k = c*8+i in [0,64), c4 = x-quarter
  const int bz = row / 48;                    // b*48+z
  const int b = bz / 48;
  // linear float index: (b*64+k)*48^3 + (row - b*48*48... ) careful: row already = (b*48+z)*48+y
  const int zy = row - b * 48 * 48;           // z*48+y
  const float* src = x + (size_t)(b * 64 + k) * (48 * 48 * 48) + (size_t)zy * 48;

  __shared__ unsigned short T[2][48][32];     // [cb][x][k32], 6144 B
  const int cb = k >> 5, k32 = k & 31;
#pragma unroll
  for (int j = 0; j < 3; ++j) {
    const int x0 = c4 * 12 + j * 4;
    float4 f = *(const float4*)(src + x0);
    T[cb][x0 + 0][k32] = f2bf(f.x);
    T[cb][x0 + 1][k32] = f2bf(f.y);
    T[cb][x0 + 2][k32] = f2bf(f.z);
    T[cb][x0 + 3][k32] = f2bf(f.w);
  }
  __syncthreads();
  uint4* dst = (uint4*)(xt + (size_t)row * (ROW_BYTES / 2));
  const uint4* srcl = (const uint4*)T;
  dst[t] = srcl[t];
  if (t < 128) dst[t + 256] = srcl[t + 256];
}

// ---- prep 2: pack A (sign-folded weights) into MFMA fragment order ----
// Apk[e], e = ((s*4+q)*64 + mi)*8 + t ; K-step s = ((m*3+l)*3+v)*2 + cb ; k_local = q*8+t
__global__ __launch_bounds__(256) void build_apk(const float* __restrict__ W,
                                                 unsigned short* __restrict__ Apk) {
  int e = blockIdx.x * 256 + threadIdx.x;  // < 110592
  int t  = e & 7;
  int mi = (e >> 3) & 63;
  int q  = (e >> 9) & 3;
  int s  = e >> 11;                 // 0..53
  int cb = s & 1, mlv = s >> 1;
  int v = mlv % 3, l = (mlv / 3) % 3, m = mlv / 9;
  int kl = cb * 32 + q * 8 + t;     // (c,i)
  int c = kl >> 3, i = kl & 7;
  int o = mi >> 3, kb = mi & 7, j = i ^ kb;
  float val = ga_sign(i, j) * W[((((m * 3 + l) * 3 + v) * 8 + c) * 8 + o) * 8 + j];
  Apk[e] = f2bf(val);
}

// ---- main: implicit GEMM ----
__global__ __launch_bounds__(256) void gpconv_mfma(
    const unsigned short* __restrict__ xt,   // [(b*48+z)*48+y][cb][x48][k32] bf16
    const unsigned short* __restrict__ Apk,  // packed A frags
    const float* __restrict__ bias,          // [64]
    float* __restrict__ out)                 // [8,64,46,46,46]
{
  const int d = blockIdx.x, hg = blockIdx.y, b = blockIdx.z;
  const int h0 = hg * 4;
  const int tid = threadIdx.x;
  const int wv = tid >> 6;          // wave id = output h row offset
  const int lane = tid & 63, r = lane & 15, q = lane >> 4;

  // [s6][cb][col][k32]; col 48,49 are zero pad for the v-shift window
  __shared__ __attribute__((aligned(16))) unsigned short Xs[6][2][50][32];

  // zero pad columns once (never overwritten: staging writes cols 0..47 linearly)
  for (int zz = tid; zz < 6 * 2 * 2 * 32; zz += 256) {
    const int kk = zz & 31, c2 = (zz >> 5) & 1, cbz = (zz >> 6) & 1, s6z = zz >> 7;
    Xs[s6z][cbz][48 + c2][kk] = 0;
  }

  f32x4 acc[4][3];
#pragma unroll
  for (int ms = 0; ms < 4; ++ms)
#pragma unroll
    for (int nt = 0; nt < 3; ++nt) acc[ms][nt] = (f32x4){0.f, 0.f, 0.f, 0.f};

  const unsigned short* Apl = Apk + q * 512 + r * 8;  // lane-hoisted A base (shorts)

#pragma unroll 1
  for (int m = 0; m < 3; ++m) {
    const int zin = d + m;
    __syncthreads();
    {
      // stage rows y = h0..h0+5, both cb halves: 36 KiB = 36 chunks of 1024 B; 9 per wave.
      // hg=11 reaches y=49 -> <=1 row over-read lands in the Apk region of d_ws (outputs masked).
      const char* gbase = (const char*)xt +
          (size_t)((b * 48 + zin) * 48 + h0) * ROW_BYTES + (size_t)lane * 16;
#pragma unroll
      for (int i = 0; i < 9; ++i) {
        const int c = wv * 9 + i;             // 0..35, wave-uniform
        const int s6 = c / 6, p = c - s6 * 6; // s6 = y row, p = 1KB part (0..5)
        const int cbp = p / 3, ip = p - cbp * 3;
        unsigned loff = (unsigned)(s6 * 6400 + cbp * 3200 + ip * 1024);
        loff = __builtin_amdgcn_readfirstlane(loff);
        gload_lds16(gbase + (size_t)s6 * ROW_BYTES + (size_t)p * 1024,
                    (char*)Xs + loff);
      }
    }
    __syncthreads();  // drains vmcnt -> staged data visible to all waves

#pragma unroll
    for (int cb = 0; cb < 2; ++cb) {
#pragma unroll
      for (int l = 0; l < 3; ++l) {
        const unsigned short* Xrow = &Xs[l + wv][cb][0][0];
#pragma unroll
        for (int v = 0; v < 3; ++v) {
          const int s = ((m * 3 + l) * 3 + v) * 2 + cb;
          frag a[4], bfr[3];
#pragma unroll
          for (int ms = 0; ms < 4; ++ms)
            a[ms] = *(const frag*)(Apl + (size_t)s * 2048 + ms * 128);
#pragma unroll
          for (int nt = 0; nt < 3; ++nt)
            bfr[nt] = *(const frag*)(Xrow + (nt * 16 + r + v) * 32 + q * 8);
#pragma unroll
          for (int ms = 0; ms < 4; ++ms)
#pragma unroll
            for (int nt = 0; nt < 3; ++nt)
              acc[ms][nt] = __builtin_amdgcn_mfma_f32_16x16x32_bf16(a[ms], bfr[nt], acc[ms][nt], 0, 0, 0);
        }
      }
    }
  }

  // epilogue: D[row=q*4+reg][col=r] per 16x16 subtile
  const int y = h0 + wv;
  if (y < DOUT) {
#pragma unroll
    for (int ms = 0; ms < 4; ++ms) {
#pragma unroll
      for (int nt = 0; nt < 3; ++nt) {
        const int w = nt * 16 + r;
        if (w < DOUT) {
#pragma unroll
          for (int reg = 0; reg < 4; ++reg) {
            const int mrow = ms * 16 + q * 4 + reg;  // o*8+k
            const size_t oidx = (((size_t)(b * 64 + mrow) * DOUT + d) * DOUT + y) * DOUT + w;
            out[oidx] = acc[ms][nt][reg] + bias[mrow];
          }
        }
      }
    }
  }
}

}  // namespace

extern "C" void kernel_launch(void* const* d_in, const int* in_sizes, int n_in,
                              void* d_out, int out_size, void* d_ws, size_t ws_size,
                              hipStream_t stream) {
  const float* x    = (const float*)d_in[0];
  const float* W    = (const float*)d_in[1];
  const float* bias = (const float*)d_in[2];
  float* out = (float*)d_out;

  unsigned short* xt  = (unsigned short*)d_ws;
  unsigned short* Apk = (unsigned short*)((char*)d_ws + XBF_BYTES);

  cvt_x<<<8 * 48 * 48, 256, 0, stream>>>(x, xt);           // 18,432 blocks
  build_apk<<<APK_ELEMS / 256, 256, 0, stream>>>(W, Apk);  // 432 blocks

  dim3 grid(DOUT, 12, 8);  // (d, h-group of 4, b) = 4416 blocks
  gpconv_mfma<<<grid, 256, 0, stream>>>(xt, Apk, bias, out);
}

// Round 2
// 588.421 us; speedup vs baseline: 1.2336x; 1.2336x over previous
//
#include <hip/hip_runtime.h>

// GPConv3D as implicit GEMM on bf16 MFMA.
// out[(o,k)][(b,d,h,w)] = sum_{m,l,v,c,i} ga_sign(i,i^k) W[m,l,v,c,o,i^k] * x[b,c,i,d+m,h+l,w+v] + bias
// M=64 (o*8+k), K=1728 = 27 taps x 64 (c*8+i), N=8*46^3.
// Round-2 version:
//  - xt layout [row=(b,z,y)][cb2][q4][x48][t8] so every 16-lane MFMA quarter reads 256
//    CONTIGUOUS LDS bytes (kills the quarter-wave bank conflict of [col][k32]).
//  - wave tile M64 x N96 (2 y-rows): halves A-fragment L1/L2 traffic per FLOP.
//  - cb-half software pipeline: stage half-plane of z+1 under compute of the other half
//    (loads span a 216-MFMA window before the barrier drain).
//  - cvt_x rewritten: per-(b,z,8y) block, contiguous 1KB/instr reads, XOR-swizzled LDS
//    transpose, contiguous 16B stores.

namespace {

constexpr int DIN = 48, DOUT = 46;
constexpr size_t X_ELEMS = 8ull * 8 * 8 * DIN * DIN * DIN;   // 56,623,104
constexpr size_t XBF_BYTES = X_ELEMS * 2;                    // 113,246,208
constexpr int APK_ELEMS = 54 * 4 * 64 * 8;                   // 110,592 bf16
constexpr int ROW_SHORTS = 2 * 4 * 48 * 8;                   // 3072 shorts per (b,z,y) row
constexpr int ROW_BYTES = ROW_SHORTS * 2;                    // 6144 B

__host__ __device__ constexpr int popc_(int v) { int c = 0; while (v) { c += v & 1; v >>= 1; } return c; }
__host__ __device__ inline float ga_sign(int a, int b) {
  int s = 0;
  for (int t = a >> 1; t; t >>= 1) s += popc_(t & b);
  return (s & 1) ? -1.0f : 1.0f;
}

__device__ inline unsigned short f2bf(float f) {  // round-to-nearest-even
  unsigned u = __builtin_bit_cast(unsigned, f);
  u += 0x7fffu + ((u >> 16) & 1u);
  return (unsigned short)(u >> 16);
}

__device__ inline void gload_lds16(const void* g, void* l) {
  __builtin_amdgcn_global_load_lds(
      (const __attribute__((address_space(1))) unsigned int*)g,
      (__attribute__((address_space(3))) unsigned int*)l, 16, 0, 0);
}

using frag  = __attribute__((ext_vector_type(8))) short;  // 8 bf16 (4 VGPRs)
using f32x4 = __attribute__((ext_vector_type(4))) float;

// ---- prep 1: x fp32 -> bf16, transposed to xt[(b*48+z)*48+y][cb][q][x48][t8] ----
// Block = (b, z, y-group of 8). Reads 64 k-runs of 1536 B (coalesced 1 KB/instr),
// XOR-swizzled LDS transpose (chunk ^= y), contiguous 48 KB store.
__global__ __launch_bounds__(256) void cvt_x(const float* __restrict__ x,
                                             unsigned short* __restrict__ xt) {
  const int bid = blockIdx.x;            // (b*48+z)*6 + yg
  const int yg = bid % 6, bz = bid / 6;  // bz = b*48+z
  const int b = bz / 48, z = bz % 48;
  const int tid = threadIdx.x;
  __shared__ __attribute__((aligned(16))) unsigned short T[8 * ROW_SHORTS];  // 49152 B
  const float* src = x + (size_t)b * 64 * 110592 + (size_t)z * 2304 + (size_t)yg * 384;
#pragma unroll
  for (int it = 0; it < 24; ++it) {
    const int i = it * 256 + tid;        // 0..6143 float4s
    const int k = i / 96, j = i - k * 96;
    const int y = j / 12, x4 = j - y * 12;
    float4 f = *(const float4*)(src + (size_t)k * 110592 + y * 48 + x4 * 4);
    const int cb = k >> 5, q = (k >> 3) & 3, t = k & 7;
    const int basek = ((y * 2 + cb) * 4 + q) * 384 + t;  // shorts, + x*8 per elem
    unsigned short bfv[4] = {f2bf(f.x), f2bf(f.y), f2bf(f.z), f2bf(f.w)};
#pragma unroll
    for (int dx = 0; dx < 4; ++dx) {
      const int xx = x4 * 4 + dx;
      T[basek + ((xx ^ y) << 3)] = bfv[dx];  // swizzle 16B-chunk index by y (y<8)
    }
  }
  __syncthreads();
  uint4* dst = (uint4*)(xt + ((size_t)bz * 48 + yg * 8) * ROW_SHORTS);
#pragma unroll
  for (int it = 0; it < 12; ++it) {
    const int C = it * 256 + tid;        // chunk 0..3071 (384 chunks per y)
    const int y = C / 384;
    const unsigned byteoff = (unsigned)(C * 16) ^ (unsigned)(y << 4);
    dst[C] = *(const uint4*)((const char*)T + byteoff);
  }
}

// ---- prep 2: pack A (sign-folded weights) into MFMA fragment order ----
// Apk[e], e = ((s*4+q)*64 + mi)*8 + t ; K-step s = ((m*3+l)*3+v)*2 + cb ; k_local = q*8+t
__global__ __launch_bounds__(256) void build_apk(const float* __restrict__ W,
                                                 unsigned short* __restrict__ Apk) {
  int e = blockIdx.x * 256 + threadIdx.x;  // < 110592
  int t  = e & 7;
  int mi = (e >> 3) & 63;
  int q  = (e >> 9) & 3;
  int s  = e >> 11;                 // 0..53
  int cb = s & 1, mlv = s >> 1;
  int v = mlv % 3, l = (mlv / 3) % 3, m = mlv / 9;
  int kl = cb * 32 + q * 8 + t;     // (c,i)
  int c = kl >> 3, i = kl & 7;
  int o = mi >> 3, kb = mi & 7, j = i ^ kb;
  float val = ga_sign(i, j) * W[((((m * 3 + l) * 3 + v) * 8 + c) * 8 + o) * 8 + j];
  Apk[e] = f2bf(val);
}

// ---- main: implicit GEMM, wave = M64 x (2y x 48w), cb-half pipelined staging ----
__global__ __launch_bounds__(256, 2) void gpconv_mfma(
    const unsigned short* __restrict__ xt,   // [row][cb][q][x48][t8] bf16
    const unsigned short* __restrict__ Apk,  // packed A frags
    const float* __restrict__ bias,          // [64]
    float* __restrict__ out)                 // [8,64,46,46,46]
{
  const int d = blockIdx.x, hg = blockIdx.y, b = blockIdx.z;
  const int h0 = hg * 8;
  const int tid = threadIdx.x;
  const int wv = tid >> 6;          // wave id: owns output rows h0 + 2*wv + {0,1}
  const int lane = tid & 63, r = lane & 15, q = lane >> 4;

  // 10 y-rows, each [cb2][q4][col48][t8]; +32 shorts tail pad for col 48/49 over-reads
  // (garbage there feeds only masked outputs w>=46).
  __shared__ __attribute__((aligned(16))) unsigned short Xs[10 * ROW_SHORTS + 32];

  f32x4 acc[4][2][3];
#pragma unroll
  for (int ms = 0; ms < 4; ++ms)
#pragma unroll
    for (int row = 0; row < 2; ++row)
#pragma unroll
      for (int nt = 0; nt < 3; ++nt) acc[ms][row][nt] = (f32x4){0.f, 0.f, 0.f, 0.f};

  const unsigned short* Apl = Apk + q * 512 + r * 8;  // lane-hoisted A base (shorts)

  // stage one cb half-plane (10 rows x 3 KB), 6-9 gloads/wave, linear LDS dest.
  // hg=5 reads rows y=48,49 -> over-read stays inside d_ws (Apk region), outputs masked.
  auto stage_half = [&](int zin, int cb) {
    const size_t R0 = (size_t)(b * 48 + zin) * 48 + h0;
#pragma unroll
    for (int i = 0; i < 3; ++i) {
      const int row = wv + i * 4;
      if (row < 10) {
        const char* g = (const char*)xt + (R0 + row) * ROW_BYTES + cb * 3072 + (size_t)lane * 16;
        unsigned loff = (unsigned)__builtin_amdgcn_readfirstlane(row * ROW_BYTES + cb * 3072);
#pragma unroll
        for (int ip = 0; ip < 3; ++ip)
          gload_lds16(g + ip * 1024, (char*)Xs + loff + ip * 1024);
      }
    }
  };

  auto compute_half = [&](int m, int cb) {
    const unsigned short* Xb = Xs + cb * 1536 + q * 384;
#pragma unroll
    for (int l = 0; l < 3; ++l) {
#pragma unroll
      for (int v = 0; v < 3; ++v) {
        const int mlv = (m * 3 + l) * 3 + v;
        frag a[4];
#pragma unroll
        for (int ms = 0; ms < 4; ++ms)
          a[ms] = *(const frag*)(Apl + (size_t)mlv * 4096 + cb * 2048 + ms * 128);
        frag bfr[2][3];
#pragma unroll
        for (int row = 0; row < 2; ++row) {
          const unsigned short* Xrow = Xb + (wv * 2 + row + l) * ROW_SHORTS + (r + v) * 8;
#pragma unroll
          for (int nt = 0; nt < 3; ++nt)
            bfr[row][nt] = *(const frag*)(Xrow + nt * 128);  // 16 lanes -> 256 contiguous B
        }
#pragma unroll
        for (int ms = 0; ms < 4; ++ms)
#pragma unroll
          for (int row = 0; row < 2; ++row)
#pragma unroll
            for (int nt = 0; nt < 3; ++nt)
              acc[ms][row][nt] = __builtin_amdgcn_mfma_f32_16x16x32_bf16(
                  a[ms], bfr[row][nt], acc[ms][row][nt], 0, 0, 0);
      }
    }
  };

  stage_half(d, 0);
  stage_half(d, 1);
  __syncthreads();
#pragma unroll 1
  for (int m = 0; m < 3; ++m) {
    compute_half(m, 0);
    __syncthreads();                      // waves done with buf0; drains prior loads
    if (m < 2) stage_half(d + m + 1, 0);  // buf0 <- next plane, flies under compute below
    compute_half(m, 1);
    __syncthreads();                      // drains buf0 loads; waves done with buf1
    if (m < 2) stage_half(d + m + 1, 1);  // buf1 <- next plane, flies under next compute
  }

  // epilogue: D[row=q*4+reg][col=r] per 16x16 subtile
#pragma unroll
  for (int row = 0; row < 2; ++row) {
    const int y = h0 + wv * 2 + row;
    if (y < DOUT) {
#pragma unroll
      for (int ms = 0; ms < 4; ++ms) {
#pragma unroll
        for (int nt = 0; nt < 3; ++nt) {
          const int w = nt * 16 + r;
          if (w < DOUT) {
#pragma unroll
            for (int reg = 0; reg < 4; ++reg) {
              const int mrow = ms * 16 + q * 4 + reg;  // o*8+k
              const size_t oidx = (((size_t)(b * 64 + mrow) * DOUT + d) * DOUT + y) * DOUT + w;
              out[oidx] = acc[ms][row][nt][reg] + bias[mrow];
            }
          }
        }
      }
    }
  }
}

}  // namespace

extern "C" void kernel_launch(void* const* d_in, const int* in_sizes, int n_in,
                              void* d_out, int out_size, void* d_ws, size_t ws_size,
                              hipStream_t stream) {
  const float* x    = (const float*)d_in[0];
  const float* W    = (const float*)d_in[1];
  const float* bias = (const float*)d_in[2];
  float* out = (float*)d_out;

  unsigned short* xt  = (unsigned short*)d_ws;
  unsigned short* Apk = (unsigned short*)((char*)d_ws + XBF_BYTES);

  cvt_x<<<8 * 48 * 6, 256, 0, stream>>>(x, xt);            // 2304 blocks
  build_apk<<<APK_ELEMS / 256, 256, 0, stream>>>(W, Apk);  // 432 blocks

  dim3 grid(DOUT, 6, 8);  // (d, h-group of 8, b) = 2208 blocks
  gpconv_mfma<<<grid, 256, 0, stream>>>(xt, Apk, bias, out);
}

// Round 3
// 532.203 us; speedup vs baseline: 1.3639x; 1.1056x over previous
//
#include <hip/hip_runtime.h>

// GPConv3D as implicit GEMM on bf16 MFMA.
// out[(o,k)][(b,d,h,w)] = sum_{m,l,v,c,i} ga_sign(i,i^k) W[m,l,v,c,o,i^k] * x[b,c,i,d+m,h+l,w+v] + bias
// M=64 (o*8+k), K=1728 = 27 taps x 64 (c*8+i), N=8*46^3.
// Round-3:
//  - explicit 2-slot register pipeline of A/B fragments across the 9 (l,v) steps
//  - stage issuance moved into step 2 of the following compute-half (same barrier epoch)
//  - s_setprio(1) around each 24-MFMA pack (T5)
//  - XCD-chunked block swizzle (2208 = 8*276): one (b,hg)-stripe per XCD -> planes L2-resident
//  - cvt_x: conflict-free LDS transpose (contig uint2 writes, stride-384 u16 gather reads)

namespace {

constexpr int DIN = 48, DOUT = 46;
constexpr size_t X_ELEMS = 8ull * 8 * 8 * DIN * DIN * DIN;   // 56,623,104
constexpr size_t XBF_BYTES = X_ELEMS * 2;                    // 113,246,208
constexpr int APK_ELEMS = 54 * 4 * 64 * 8;                   // 110,592 bf16
constexpr int ROW_SHORTS = 2 * 4 * 48 * 8;                   // 3072 shorts per (b,z,y) row
constexpr int ROW_BYTES = ROW_SHORTS * 2;                    // 6144 B

__host__ __device__ constexpr int popc_(int v) { int c = 0; while (v) { c += v & 1; v >>= 1; } return c; }
__host__ __device__ inline float ga_sign(int a, int b) {
  int s = 0;
  for (int t = a >> 1; t; t >>= 1) s += popc_(t & b);
  return (s & 1) ? -1.0f : 1.0f;
}

__device__ inline unsigned short f2bf(float f) {  // round-to-nearest-even
  unsigned u = __builtin_bit_cast(unsigned, f);
  u += 0x7fffu + ((u >> 16) & 1u);
  return (unsigned short)(u >> 16);
}

__device__ inline void gload_lds16(const void* g, void* l) {
  __builtin_amdgcn_global_load_lds(
      (const __attribute__((address_space(1))) unsigned int*)g,
      (__attribute__((address_space(3))) unsigned int*)l, 16, 0, 0);
}

using frag  = __attribute__((ext_vector_type(8))) short;  // 8 bf16 (4 VGPRs)
using f32x4 = __attribute__((ext_vector_type(4))) float;

// ---- prep 1: x fp32 -> bf16, transposed to xt[(b*48+z)*48+y][cb][q][x48][t8] ----
// Block = (b, z, y-group of 8). Coalesced float4 reads, LDS [k][y][x] with contiguous
// uint2 writes (conflict-free), gather-transpose reads at stride 384 shorts (conflict-free),
// contiguous uint4 stores.
__global__ __launch_bounds__(256) void cvt_x(const float* __restrict__ x,
                                             unsigned short* __restrict__ xt) {
  const int bid = blockIdx.x;            // (b*48+z)*6 + yg
  const int yg = bid % 6, bz = bid / 6;  // bz = b*48+z
  const int b = bz / 48, z = bz - b * 48;
  const int tid = threadIdx.x;
  __shared__ __attribute__((aligned(16))) unsigned short T[64 * 8 * 48];  // [k][y][x] 49152 B
  const float* src = x + (size_t)b * 64 * 110592 + (size_t)z * 2304 + (size_t)yg * 384;
#pragma unroll
  for (int it = 0; it < 24; ++it) {
    const int i = it * 256 + tid;        // 0..6143 float4s
    const int k = i / 96, j = i - k * 96;
    const int y = j / 12, x4 = j - y * 12;
    float4 f = *(const float4*)(src + (size_t)k * 110592 + y * 48 + x4 * 4);
    uint2 p;
    p.x = (unsigned)f2bf(f.x) | ((unsigned)f2bf(f.y) << 16);
    p.y = (unsigned)f2bf(f.z) | ((unsigned)f2bf(f.w) << 16);
    *(uint2*)&T[(k * 8 + y) * 48 + x4 * 4] = p;
  }
  __syncthreads();
  uint4* dst = (uint4*)(xt + ((size_t)bz * 48 + yg * 8) * ROW_SHORTS);
#pragma unroll
  for (int it = 0; it < 12; ++it) {
    const int C = it * 256 + tid;        // chunk 0..3071 (384 per y-row)
    const int y = C / 384, rem = C - y * 384;
    const int kq = rem / 48, xx = rem - kq * 48;   // kq = cb*4+q
    const unsigned short* p0 = &T[(kq * 64 + y) * 48 + xx];  // + t*384 per t
    const unsigned s0 = p0[0],    s1 = p0[384],  s2 = p0[768],  s3 = p0[1152];
    const unsigned s4 = p0[1536], s5 = p0[1920], s6 = p0[2304], s7 = p0[2688];
    uint4 o;
    o.x = s0 | (s1 << 16); o.y = s2 | (s3 << 16);
    o.z = s4 | (s5 << 16); o.w = s6 | (s7 << 16);
    dst[C] = o;
  }
}

// ---- prep 2: pack A (sign-folded weights) into MFMA fragment order ----
// Apk[e], e = ((s*4+q)*64 + mi)*8 + t ; K-step s = ((m*3+l)*3+v)*2 + cb ; k_local = q*8+t
__global__ __launch_bounds__(256) void build_apk(const float* __restrict__ W,
                                                 unsigned short* __restrict__ Apk) {
  int e = blockIdx.x * 256 + threadIdx.x;  // < 110592
  int t  = e & 7;
  int mi = (e >> 3) & 63;
  int q  = (e >> 9) & 3;
  int s  = e >> 11;                 // 0..53
  int cb = s & 1, mlv = s >> 1;
  int v = mlv % 3, l = (mlv / 3) % 3, m = mlv / 9;
  int kl = cb * 32 + q * 8 + t;     // (c,i)
  int c = kl >> 3, i = kl & 7;
  int o = mi >> 3, kb = mi & 7, j = i ^ kb;
  float val = ga_sign(i, j) * W[((((m * 3 + l) * 3 + v) * 8 + c) * 8 + o) * 8 + j];
  Apk[e] = f2bf(val);
}

// ---- main: implicit GEMM, wave = M64 x (2y x 48w), register-pipelined (l,v) steps ----
__global__ __launch_bounds__(256, 2) void gpconv_mfma(
    const unsigned short* __restrict__ xt,   // [row][cb][q][x48][t8] bf16
    const unsigned short* __restrict__ Apk,  // packed A frags
    const float* __restrict__ bias,          // [64]
    float* __restrict__ out)                 // [8,64,46,46,46]
{
  // XCD-chunked bijective swizzle: 2208 blocks = 8 XCD * 276.
  // Each XCD gets 6 (b,hg)-stripes, d-contiguous -> ~2.9 MB working set per stripe (L2-fit).
  const int fid0 = blockIdx.x + 46 * (blockIdx.y + 6 * blockIdx.z);
  const int fid = (fid0 & 7) * 276 + (fid0 >> 3);
  const int d = fid % 46;
  const int t6 = fid / 46;          // hg + 6*b
  const int hg = t6 % 6, b = t6 / 6;
  const int h0 = hg * 8;
  const int tid = threadIdx.x;
  const int wv = tid >> 6;          // wave id: owns output rows h0 + 2*wv + {0,1}
  const int lane = tid & 63, r = lane & 15, q = lane >> 4;

  // 10 y-rows, each [cb2][q4][col48][t8]; +32 shorts tail pad for col 48/49 over-reads
  // (garbage there feeds only masked outputs w>=46).
  __shared__ __attribute__((aligned(16))) unsigned short Xs[10 * ROW_SHORTS + 32];

  f32x4 acc[4][2][3];
#pragma unroll
  for (int ms = 0; ms < 4; ++ms)
#pragma unroll
    for (int row = 0; row < 2; ++row)
#pragma unroll
      for (int nt = 0; nt < 3; ++nt) acc[ms][row][nt] = (f32x4){0.f, 0.f, 0.f, 0.f};

  const unsigned short* Apl = Apk + q * 512 + r * 8;  // lane-hoisted A base (shorts)

  // stage one cb half-plane (10 rows x 3 KB), 6-9 gloads/wave, linear LDS dest.
  // hg=5 reads rows y=48,49 -> over-read stays inside d_ws (Apk region), outputs masked.
  auto stage_half = [&](int zin, int cb) {
    const size_t R0 = (size_t)(b * 48 + zin) * 48 + h0;
#pragma unroll
    for (int i = 0; i < 3; ++i) {
      const int row = wv + i * 4;
      if (row < 10) {
        const char* g = (const char*)xt + (R0 + row) * ROW_BYTES + cb * 3072 + (size_t)lane * 16;
        unsigned loff = (unsigned)__builtin_amdgcn_readfirstlane(row * ROW_BYTES + cb * 3072);
#pragma unroll
        for (int ip = 0; ip < 3; ++ip)
          gload_lds16(g + ip * 1024, (char*)Xs + loff + ip * 1024);
      }
    }
  };

  // 9 (l,v) steps, 2-slot register pipeline; optional staging issued at step 2
  // (post-barrier epoch of the buffer being overwritten; lands under ~7 MFMA packs).
  auto compute_half = [&](int m, int cb, bool do_stage, int stage_z, int stage_cb) {
    const unsigned short* Xb = Xs + cb * 1536 + q * 384;
    const unsigned short* Ab = Apl + (size_t)m * 9 * 4096 + cb * 2048;
    frag a[2][4];
    frag bfr[2][2][3];
#pragma unroll
    for (int ms = 0; ms < 4; ++ms) a[0][ms] = *(const frag*)(Ab + ms * 128);
#pragma unroll
    for (int row = 0; row < 2; ++row) {
      const unsigned short* Xrow = Xb + (wv * 2 + row) * ROW_SHORTS + r * 8;
#pragma unroll
      for (int nt = 0; nt < 3; ++nt) bfr[0][row][nt] = *(const frag*)(Xrow + nt * 128);
    }
#pragma unroll
    for (int s = 0; s < 9; ++s) {
      const int cur = s & 1, nxt = cur ^ 1;
      if (s < 8) {
        const int l = (s + 1) / 3, v = (s + 1) - l * 3;
#pragma unroll
        for (int ms = 0; ms < 4; ++ms)
          a[nxt][ms] = *(const frag*)(Ab + (s + 1) * 4096 + ms * 128);
#pragma unroll
        for (int row = 0; row < 2; ++row) {
          const unsigned short* Xrow = Xb + (wv * 2 + row + l) * ROW_SHORTS + (r + v) * 8;
#pragma unroll
          for (int nt = 0; nt < 3; ++nt)
            bfr[nxt][row][nt] = *(const frag*)(Xrow + nt * 128);
        }
      }
      if (s == 2 && do_stage) stage_half(stage_z, stage_cb);
      __builtin_amdgcn_s_setprio(1);
#pragma unroll
      for (int ms = 0; ms < 4; ++ms)
#pragma unroll
        for (int row = 0; row < 2; ++row)
#pragma unroll
          for (int nt = 0; nt < 3; ++nt)
            acc[ms][row][nt] = __builtin_amdgcn_mfma_f32_16x16x32_bf16(
                a[cur][ms], bfr[cur][row][nt], acc[ms][row][nt], 0, 0, 0);
      __builtin_amdgcn_s_setprio(0);
    }
  };

  stage_half(d, 0);
  stage_half(d, 1);
  __syncthreads();
#pragma unroll 1
  for (int m = 0; m < 3; ++m) {
    // buf1 <- plane d+m staged inside (for m>=1); needed by compute(m,1) after the sync.
    compute_half(m, 0, m >= 1, d + m, 1);
    __syncthreads();
    // buf0 <- plane d+m+1 staged inside (for m<2); needed by compute(m+1,0) after the sync.
    compute_half(m, 1, m < 2, d + m + 1, 0);
    __syncthreads();
  }

  // epilogue: D[row=q*4+reg][col=r] per 16x16 subtile
#pragma unroll
  for (int row = 0; row < 2; ++row) {
    const int y = h0 + wv * 2 + row;
    if (y < DOUT) {
#pragma unroll
      for (int ms = 0; ms < 4; ++ms) {
#pragma unroll
        for (int nt = 0; nt < 3; ++nt) {
          const int w = nt * 16 + r;
          if (w < DOUT) {
#pragma unroll
            for (int reg = 0; reg < 4; ++reg) {
              const int mrow = ms * 16 + q * 4 + reg;  // o*8+k
              const size_t oidx = (((size_t)(b * 64 + mrow) * DOUT + d) * DOUT + y) * DOUT + w;
              out[oidx] = acc[ms][row][nt][reg] + bias[mrow];
            }
          }
        }
      }
    }
  }
}

}  // namespace

extern "C" void kernel_launch(void* const* d_in, const int* in_sizes, int n_in,
                              void* d_out, int out_size, void* d_ws, size_t ws_size,
                              hipStream_t stream) {
  const float* x    = (const float*)d_in[0];
  const float* W    = (const float*)d_in[1];
  const float* bias = (const float*)d_in[2];
  float* out = (float*)d_out;

  unsigned short* xt  = (unsigned short*)d_ws;
  unsigned short* Apk = (unsigned short*)((char*)d_ws + XBF_BYTES);

  cvt_x<<<8 * 48 * 6, 256, 0, stream>>>(x, xt);            // 2304 blocks
  build_apk<<<APK_ELEMS / 256, 256, 0, stream>>>(W, Apk);  // 432 blocks

  dim3 grid(DOUT, 6, 8);  // (d, h-group of 8, b) = 2208 blocks
  gpconv_mfma<<<grid, 256, 0, stream>>>(xt, Apk, bias, out);
}